// Round 1
// baseline (15860.495 us; speedup 1.0000x reference)
//
#include <hip/hip_runtime.h>

// ---------------------------------------------------------------------------
// 2-layer GRU (Keras reset_after=true), B=64, T=1024, D=U=512.
// Round-4 structure:
//  PHASE 1: xg0 = x @ W0 precomputed by ALL 256 WGs as a parallel GEMM
//           (removes the HBM-latency x-pass + cvt8 VALU from the recurrence).
//           Stored fp32 [t][slice][g][row32][24] via agent-scope stores.
//  grid barrier (verified leaf/root code), then cell1 WGs repack W1/U1.
//  PHASE 2: recurrence. cell0 step = ONE pass (h0@U0) + epilogue(+xg).
//           cell1 step = own pass (h1@U1) then cross pass (h0@W1).
//  SYNC: per-slice flag vector g_flags[cell][g][64] (16B stride), value =
//        (epoch+1)*1024 + steps_done (monotone across launches, stale-safe).
//        Producer: one relaxed agent store after __syncthreads drain.
//        Consumer: wave0 loads 64 flags in parallel, __all() ballot, sleep(1).
//  - split-bf16 (hi+lo) MFMA, 3 mfma per tile => ~fp32 accuracy (unchanged).
//  - gemm unroll 4 -> 8 (more loads in flight; VGPR headroom at 1 wave/SIMD).
//  - h_prev kept in a register (was LDS).
// ---------------------------------------------------------------------------

typedef __bf16 bf16x8 __attribute__((ext_vector_type(8)));
typedef float  f32x4  __attribute__((ext_vector_type(4)));
typedef unsigned int uint4v __attribute__((ext_vector_type(4)));

#define T_STEPS 1024
#define NWG 256
#define NTHR 256
#define SMEM_BYTES (98304 + 4096 + 1024 + 128 + 32)

// h0[k] at slot k+1 (slot 0 = zeros); h1[t] at slot t+1. 134 MB each.
__device__ __align__(16) unsigned int g_h0[1025LL * 64 * 512];
__device__ __align__(16) unsigned int g_h1[1025LL * 64 * 512];
// xg0 = x @ W0 (no bias): [t][slice(64)][g(2)][row(32)][24] fp32, 402 MB
__device__ __align__(16) float g_xg[1024LL * 64 * 2 * 32 * 24];
// one-time init barrier state (BSS zero; monotone across launches)
__device__ unsigned int g_leaf[8 * 64];
__device__ unsigned int g_root[64];
__device__ unsigned int g_epoch[64];
// per-slice step flags, 16B stride (4 lines per clique); monotone across launches
__device__ __align__(256) unsigned int g_flags[2][2][256];   // [cell][g][slice*4]

__device__ __forceinline__ void f2hilo(float f, unsigned short& hi, unsigned short& lo) {
    __bf16 h = (__bf16)f;
    float  fh = (float)h;
    __bf16 l = (__bf16)(f - fh);
    hi = __builtin_bit_cast(unsigned short, h);
    lo = __builtin_bit_cast(unsigned short, l);
}

__device__ __forceinline__ f32x4 mfma16(bf16x8 a, bf16x8 b, f32x4 c) {
    return __builtin_amdgcn_mfma_f32_16x16x32_bf16(a, b, c, 0, 0, 0);
}

__device__ __forceinline__ void unpack8(const unsigned int* p, bf16x8& ah, bf16x8& al) {
    uint4v v0 = *(const uint4v*)p;
    uint4v v1 = *(const uint4v*)(p + 4);
    uint4v h, l;
    h.x = __builtin_amdgcn_perm(v0.y, v0.x, 0x07060302u);
    h.y = __builtin_amdgcn_perm(v0.w, v0.z, 0x07060302u);
    h.z = __builtin_amdgcn_perm(v1.y, v1.x, 0x07060302u);
    h.w = __builtin_amdgcn_perm(v1.w, v1.z, 0x07060302u);
    l.x = __builtin_amdgcn_perm(v0.y, v0.x, 0x05040100u);
    l.y = __builtin_amdgcn_perm(v0.w, v0.z, 0x05040100u);
    l.z = __builtin_amdgcn_perm(v1.y, v1.x, 0x05040100u);
    l.w = __builtin_amdgcn_perm(v1.w, v1.z, 0x05040100u);
    ah = __builtin_bit_cast(bf16x8, h);
    al = __builtin_bit_cast(bf16x8, l);
}

__device__ __forceinline__ void cvt8(const float* p, bf16x8& ah, bf16x8& al) {
    float4 a = *(const float4*)p;
    float4 b = *(const float4*)(p + 4);
    float f[8] = {a.x, a.y, a.z, a.w, b.x, b.y, b.z, b.w};
    bf16x8 h, l;
    #pragma unroll
    for (int i = 0; i < 8; ++i) {
        __bf16 hv = (__bf16)f[i];
        h[i] = hv;
        l[i] = (__bf16)(f[i] - (float)hv);
    }
    ah = h; al = l;
}

// one GEMM pass (verified logic, streaming loads, unroll 8)
__device__ __forceinline__ void gemm_pass(
    bool useX, int pass, int ntile, int lane, int lcol, int kch,
    const float* A0x, const unsigned int* Ap,
    const unsigned short* sBhi, const unsigned short* sBlo,
    f32x4& acc_zr, f32x4& acc_xh, f32x4& acc_hh)
{
    bf16x8 bzero = {};
    if (ntile == 0) {
        #pragma unroll 8
        for (int ks = 0; ks < 16; ++ks) {
            bf16x8 ah, al;
            if (useX) cvt8(A0x + ks * 32 + kch * 8, ah, al);
            else      unpack8(Ap + ks * 32 + kch * 8, ah, al);
            const int o = pass * 12288 + ks * 512 + lane * 8;
            bf16x8 bh = *(const bf16x8*)(sBhi + o);
            bf16x8 bl = *(const bf16x8*)(sBlo + o);
            acc_zr = mfma16(ah, bh, acc_zr);
            acc_zr = mfma16(ah, bl, acc_zr);
            acc_zr = mfma16(al, bh, acc_zr);
        }
    } else {
        #pragma unroll 8
        for (int ks = 0; ks < 16; ++ks) {
            bf16x8 ah, al;
            if (useX) cvt8(A0x + ks * 32 + kch * 8, ah, al);
            else      unpack8(Ap + ks * 32 + kch * 8, ah, al);
            bf16x8 bh = bzero, bl = bzero;
            if (lcol < 8) {
                const int e = kch * 8 + lcol;
                const int o = pass * 12288 + 8192 + ks * 256 + e * 8;
                bh = *(const bf16x8*)(sBhi + o);
                bl = *(const bf16x8*)(sBlo + o);
            }
            f32x4 acc = pass ? acc_hh : acc_xh;
            acc = mfma16(ah, bh, acc);
            acc = mfma16(ah, bl, acc);
            acc = mfma16(al, bh, acc);
            if (pass) acc_hh = acc; else acc_xh = acc;
        }
    }
}

// pack a weight slice into LDS (B-frag layout), bf16 hi/lo
__device__ __forceinline__ void pack_weights(
    const float* Wm, const float* Um, int c0, int tid,
    unsigned short* sBhi, unsigned short* sBlo)
{
    for (int e = tid; e < 24576; e += NTHR) {
        const int pass = e / 12288;
        const int rem  = e % 12288;
        int j, gcol;
        if (rem < 8192) {
            const int ks = rem >> 9, r2 = rem & 511;
            const int entry = r2 >> 3, i = r2 & 7;
            const int col = entry & 15, kch = entry >> 4;
            j = ks * 32 + kch * 8 + i;
            gcol = (col < 8) ? (c0 + col) : (512 + c0 + col - 8);
        } else {
            const int r2 = rem - 8192;
            const int ks = r2 >> 8, r3 = r2 & 255;
            const int entry = r3 >> 3, i = r3 & 7;
            const int col = entry & 7, kch = entry >> 3;
            j = ks * 32 + kch * 8 + i;
            gcol = 1024 + c0 + col;
        }
        const float v = (pass ? Um : Wm)[j * 1536 + gcol];
        f2hilo(v, sBhi[e], sBlo[e]);
    }
}

// epilogue: accs (+optional precomputed xg) -> gates -> hn (per thread ml,col)
__device__ __forceinline__ float epilogue_hn(
    int tid, int mtile, int ntile, int lane, int lcol,
    const f32x4& acc_zr, const f32x4& acc_xh, const f32x4& acc_hh,
    float* sAcc, const float* sBias, float hp,
    bool useXg, float xgz, float xgr, float xgh)
{
    const int drow = mtile * 16 + (lane >> 4) * 4;
    if (ntile == 0) {
        #pragma unroll
        for (int r2 = 0; r2 < 4; ++r2) sAcc[(drow + r2) * 16 + lcol] = acc_zr[r2];
    } else if (lcol < 8) {
        #pragma unroll
        for (int r2 = 0; r2 < 4; ++r2) {
            if (!useXg) sAcc[512 + (drow + r2) * 8 + lcol] = acc_xh[r2];
            sAcc[768 + (drow + r2) * 8 + lcol] = acc_hh[r2];
        }
    }
    __syncthreads();
    const int ml  = tid >> 3;
    const int col = tid & 7;
    float zp = sAcc[ml * 16 + col]     + sBias[col];
    float rp = sAcc[ml * 16 + 8 + col] + sBias[8 + col];
    if (useXg) { zp += xgz; rp += xgr; }
    const float z = 1.f / (1.f + __expf(-zp));
    const float r = 1.f / (1.f + __expf(-rp));
    const float xh = (useXg ? xgh : sAcc[512 + ml * 8 + col]) + sBias[16 + col];
    const float hh = sAcc[768 + ml * 8 + col] + sBias[24 + col];
    const float ct = tanhf(xh + r * hh);
    return z * hp + (1.f - z) * ct;
}

// wave0 polls all 64 slice-flags in parallel; release WG when all >= target
__device__ __forceinline__ void wait_flags(unsigned int* F, unsigned int target, int tid) {
    if (tid < 64) {
        for (;;) {
            unsigned int v = __hip_atomic_load(&F[tid * 4], __ATOMIC_RELAXED,
                                               __HIP_MEMORY_SCOPE_AGENT);
            if (__all((int)(v - target) >= 0)) break;
            __builtin_amdgcn_s_sleep(1);
        }
    }
    __syncthreads();
}

__global__ void __launch_bounds__(NTHR, 1) gru_persistent(
    const float* __restrict__ x,  const float* __restrict__ W0,
    const float* __restrict__ U0, const float* __restrict__ b0,
    const float* __restrict__ W1, const float* __restrict__ U1,
    const float* __restrict__ b1, float* __restrict__ out)
{
    extern __shared__ char smem[];
    unsigned short* sBhi = (unsigned short*)smem;
    unsigned short* sBlo = sBhi + 24576;
    float* sAcc   = (float*)(smem + 98304);
    float* sBias  = sAcc + 1024 + 256;          // (old sHprev slot unused)
    unsigned int* sE0 = (unsigned int*)(sBias + 32);

    const int wg    = blockIdx.x;
    const int g     = wg >> 7;
    const int cell  = (wg >> 6) & 1;
    const int slice = wg & 63;
    const int c0    = slice * 8;
    const int tid   = threadIdx.x;

    // kill stale L1/L2 lines from a previous launch
    __builtin_amdgcn_fence(__ATOMIC_ACQUIRE, "agent");

    if (tid == 0)
        sE0[0] = __hip_atomic_load(&g_epoch[0], __ATOMIC_RELAXED, __HIP_MEMORY_SCOPE_AGENT);

    // zero own region of slot 0 (h[-1] = 0)
    {
        const int mlz = tid >> 3, colz = tid & 7;
        unsigned int* dst = (cell ? g_h1 : g_h0)
                          + (long long)(g * 32 + mlz) * 512 + (c0 + colz);
        __hip_atomic_store(dst, 0u, __ATOMIC_RELAXED, __HIP_MEMORY_SCOPE_AGENT);
    }

    // phase-1 weights: W0 -> pass0 region, U0 -> pass1 region (ALL WGs)
    pack_weights(W0, U0, c0, tid, sBhi, sBlo);

    // biases for own cell (used only in phase 2)
    {
        const float* b = cell ? b1 : b0;
        if (tid < 32) {
            const int col = tid & 7, sec = tid >> 3;
            float v;
            if (sec == 0)      v = b[c0 + col] + b[1536 + c0 + col];
            else if (sec == 1) v = b[512 + c0 + col] + b[1536 + 512 + c0 + col];
            else if (sec == 2) v = b[1024 + c0 + col];
            else               v = b[1536 + 1024 + c0 + col];
            sBias[tid] = v;
        }
    }
    __syncthreads();
    const unsigned int E0 = sE0[0];
    const unsigned int EB = (E0 + 1u) << 10;   // epoch-extended flag base

    const int lane  = tid & 63;
    const int mtile = (tid >> 6) & 1;
    const int ntile = tid >> 7;
    const int lcol  = lane & 15;
    const int kch   = lane >> 4;
    const int arow  = g * 32 + mtile * 16 + lcol;
    const int ml    = tid >> 3;
    const int colw  = tid & 7;

    // ---- PHASE 1: xg = x @ W0 for t in quarter q, all b ----
    {
        const int q = wg >> 6;   // 0..3 -> t in [q*256, q*256+256)
        for (int bb = 0; bb < 64; ++bb) {
            for (int j = 0; j < 8; ++j) {
                const int t0 = q * 256 + j * 32;
                f32x4 acc_zr = {0.f, 0.f, 0.f, 0.f};
                f32x4 acc_xh = {0.f, 0.f, 0.f, 0.f};
                f32x4 acc_hh = {0.f, 0.f, 0.f, 0.f};
                const float* A = x + ((long long)bb * 1024 + t0 + mtile * 16 + lcol) * 512;
                gemm_pass(true, 0, ntile, lane, lcol, kch, A, nullptr,
                          sBhi, sBlo, acc_zr, acc_xh, acc_hh);
                __syncthreads();   // prior iter's sAcc reads done
                const int drow = mtile * 16 + (lane >> 4) * 4;
                if (ntile == 0) {
                    #pragma unroll
                    for (int r2 = 0; r2 < 4; ++r2) sAcc[(drow + r2) * 16 + lcol] = acc_zr[r2];
                } else if (lcol < 8) {
                    #pragma unroll
                    for (int r2 = 0; r2 < 4; ++r2) sAcc[512 + (drow + r2) * 8 + lcol] = acc_xh[r2];
                }
                __syncthreads();
                const float zv = sAcc[ml * 16 + colw];
                const float rv = sAcc[ml * 16 + 8 + colw];
                const float hv = sAcc[512 + ml * 8 + colw];
                float* dst = g_xg + (long long)(t0 + ml) * 98304
                           + slice * 1536 + (bb >> 5) * 768 + (bb & 31) * 24 + colw;
                __hip_atomic_store((unsigned int*)dst,
                    __builtin_bit_cast(unsigned int, zv), __ATOMIC_RELAXED, __HIP_MEMORY_SCOPE_AGENT);
                __hip_atomic_store((unsigned int*)(dst + 8),
                    __builtin_bit_cast(unsigned int, rv), __ATOMIC_RELAXED, __HIP_MEMORY_SCOPE_AGENT);
                __hip_atomic_store((unsigned int*)(dst + 16),
                    __builtin_bit_cast(unsigned int, hv), __ATOMIC_RELAXED, __HIP_MEMORY_SCOPE_AGENT);
                // store acks overlap the next call's gemm; drained at its barrier
            }
        }
    }
    __syncthreads();   // per-wave vmcnt(0) drain before grid barrier

    // ---- grid barrier (xg + slot0 zeros now safe everywhere) ----
    {
        const unsigned int target = E0 + 1u;
        if (tid == 0) {
            asm volatile("s_waitcnt vmcnt(0)" ::: "memory");
            unsigned int o = __hip_atomic_fetch_add(&g_leaf[(wg & 7) * 64], 1u,
                                __ATOMIC_RELAXED, __HIP_MEMORY_SCOPE_AGENT);
            if (o == 32u * target - 1u) {
                unsigned int r = __hip_atomic_fetch_add(&g_root[0], 1u,
                                    __ATOMIC_RELAXED, __HIP_MEMORY_SCOPE_AGENT);
                if (r == 8u * target - 1u)
                    __hip_atomic_store(&g_epoch[0], target,
                                       __ATOMIC_RELAXED, __HIP_MEMORY_SCOPE_AGENT);
            }
        }
        while ((int)(__hip_atomic_load(&g_epoch[0], __ATOMIC_RELAXED,
                                       __HIP_MEMORY_SCOPE_AGENT) - target) < 0)
            __builtin_amdgcn_s_sleep(1);
        asm volatile("" ::: "memory");
        __syncthreads();
    }

    // ---- repack for phase 2: cell1 needs W1/U1 (cell0 keeps U0 in pass1) ----
    if (cell == 1) {
        pack_weights(W1, U1, c0, tid, sBhi, sBlo);
        __syncthreads();
    }

    float hprev = 0.f;

    if (cell == 0) {
        unsigned int* const myF  = &g_flags[0][g][slice * 4];
        unsigned int* const ownF = &g_flags[0][g][0];
        for (int k = 0; k < T_STEPS; ++k) {
            // issue xg loads first: latency hides under the flag wait
            const float* xgp = g_xg + (long long)k * 98304
                             + slice * 1536 + g * 768 + ml * 24 + colw;
            const float xgz = xgp[0], xgr = xgp[8], xgh = xgp[16];

            if (k > 0) wait_flags(ownF, EB + (unsigned int)k, tid);

            f32x4 acc_zr = {0.f, 0.f, 0.f, 0.f};
            f32x4 acc_xh = {0.f, 0.f, 0.f, 0.f};
            f32x4 acc_hh = {0.f, 0.f, 0.f, 0.f};
            const unsigned int* A1p = g_h0 + (long long)k * (64 * 512) + arow * 512;
            gemm_pass(false, 1, ntile, lane, lcol, kch, nullptr, A1p,
                      sBhi, sBlo, acc_zr, acc_xh, acc_hh);

            const float hn = epilogue_hn(tid, mtile, ntile, lane, lcol,
                                         acc_zr, acc_xh, acc_hh, sAcc, sBias,
                                         hprev, true, xgz, xgr, xgh);
            hprev = hn;
            {
                unsigned short hi_, lo_;
                f2hilo(hn, hi_, lo_);
                const unsigned int pk = ((unsigned int)hi_ << 16) | (unsigned int)lo_;
                unsigned int* dst = g_h0 + (long long)(k + 1) * (64 * 512)
                                  + (long long)(g * 32 + ml) * 512 + (c0 + colw);
                __hip_atomic_store(dst, pk, __ATOMIC_RELAXED, __HIP_MEMORY_SCOPE_AGENT);
            }
            __syncthreads();   // per-wave vmcnt(0) drain before flag
            if (tid == 0)
                __hip_atomic_store(myF, EB + (unsigned int)(k + 1),
                                   __ATOMIC_RELAXED, __HIP_MEMORY_SCOPE_AGENT);
        }
    } else {
        unsigned int* const myF  = &g_flags[1][g][slice * 4];
        unsigned int* const ownF = &g_flags[1][g][0];
        unsigned int* const upF  = &g_flags[0][g][0];
        for (int t = 0; t < T_STEPS; ++t) {
            if (t > 0) wait_flags(ownF, EB + (unsigned int)t, tid);

            f32x4 acc_zr = {0.f, 0.f, 0.f, 0.f};
            f32x4 acc_xh = {0.f, 0.f, 0.f, 0.f};
            f32x4 acc_hh = {0.f, 0.f, 0.f, 0.f};

            // own-recurrence pass first: h1[t-1] @ U1 (overlaps upstream lag)
            const unsigned int* A1p = g_h1 + (long long)t * (64 * 512) + arow * 512;
            gemm_pass(false, 1, ntile, lane, lcol, kch, nullptr, A1p,
                      sBhi, sBlo, acc_zr, acc_xh, acc_hh);

            // wait upstream: h0[t]
            wait_flags(upF, EB + (unsigned int)(t + 1), tid);

            const unsigned int* A0p = g_h0 + (long long)(t + 1) * (64 * 512) + arow * 512;
            gemm_pass(false, 0, ntile, lane, lcol, kch, nullptr, A0p,
                      sBhi, sBlo, acc_zr, acc_xh, acc_hh);

            const float hn = epilogue_hn(tid, mtile, ntile, lane, lcol,
                                         acc_zr, acc_xh, acc_hh, sAcc, sBias,
                                         hprev, false, 0.f, 0.f, 0.f);
            hprev = hn;
            {
                unsigned short hi_, lo_;
                f2hilo(hn, hi_, lo_);
                const unsigned int pk = ((unsigned int)hi_ << 16) | (unsigned int)lo_;
                unsigned int* dst = g_h1 + (long long)(t + 1) * (64 * 512)
                                  + (long long)(g * 32 + ml) * 512 + (c0 + colw);
                __hip_atomic_store(dst, pk, __ATOMIC_RELAXED, __HIP_MEMORY_SCOPE_AGENT);
                if (t == T_STEPS - 1)
                    out[(g * 32 + ml) * 512 + (c0 + colw)] = hn;
            }
            __syncthreads();
            if (tid == 0)
                __hip_atomic_store(myF, EB + (unsigned int)(t + 1),
                                   __ATOMIC_RELAXED, __HIP_MEMORY_SCOPE_AGENT);
        }
    }
}

extern "C" void kernel_launch(void* const* d_in, const int* in_sizes, int n_in,
                              void* d_out, int out_size, void* d_ws, size_t ws_size,
                              hipStream_t stream) {
    (void)in_sizes; (void)n_in; (void)d_ws; (void)ws_size; (void)out_size;
    const float* x  = (const float*)d_in[0];
    const float* W0 = (const float*)d_in[1];
    const float* U0 = (const float*)d_in[2];
    const float* b0 = (const float*)d_in[3];
    const float* W1 = (const float*)d_in[4];
    const float* U1 = (const float*)d_in[5];
    const float* b1 = (const float*)d_in[6];
    float* out = (float*)d_out;

    (void)hipFuncSetAttribute((const void*)gru_persistent,
                              hipFuncAttributeMaxDynamicSharedMemorySize, SMEM_BYTES);
    void* args[] = {&x, &W0, &U0, &b0, &W1, &U1, &b1, &out};
    hipError_t e = hipLaunchCooperativeKernel((const void*)gru_persistent,
                                              dim3(NWG), dim3(NTHR),
                                              args, SMEM_BYTES, stream);
    if (e != hipSuccess) {
        gru_persistent<<<dim3(NWG), dim3(NTHR), SMEM_BYTES, stream>>>(
            x, W0, U0, b0, W1, U1, b1, out);
    }
}

// Round 2
// 13211.046 us; speedup vs baseline: 1.2005x; 1.2005x over previous
//
#include <hip/hip_runtime.h>

// ---------------------------------------------------------------------------
// 2-layer GRU (Keras reset_after=true), B=64, T=1024, D=U=512.
// Round-5 structure (fixes round-4 regression: cell1 2-pass serial chain +
// cell0 runaway causing cold-HBM h0 reads):
//  PHASE 1: xg0 = x @ W0 precomputed by ALL 256 WGs (unchanged concept),
//           now gate-contiguous layout (3 floats/thread) + staged loads.
//  PHASE 2: cell0 step = wait + h0@U0 + epilogue(+xg, prefetched 1 step).
//           cell1 step = wait-up + h0@W1 (overlaps own-wait) + wait-own +
//                        h1@U1 + epilogue.  -> both cells: ONE pass on chain.
//           cell0 BACKPRESSURE: lead over cell1 capped at 8 steps so h0
//           stays L2/L3-hot for cell1 (round-4's cold-read mode removed).
//  SYNC: per-WAVE flags g_flags[cell][g][slice*4+wave] (4/slice, 16B/slice).
//        Producer wave: h-stores -> s_waitcnt vmcnt(0) -> lane0 flag store.
//        Consumer: wave0 polls 256 flags via 2x u64 atomic loads/lane, __all.
//  GEMM: A staged into registers (32 dwordx4 in flight) before compute --
//        round-4's VGPR_Count=56 showed ~6-deep MLP; now one latency round.
//  - split-bf16 (hi+lo) MFMA, 3 mfma per tile => ~fp32 accuracy (unchanged).
// ---------------------------------------------------------------------------

typedef __bf16 bf16x8 __attribute__((ext_vector_type(8)));
typedef float  f32x4  __attribute__((ext_vector_type(4)));
typedef unsigned int uint4v __attribute__((ext_vector_type(4)));

#define T_STEPS 1024
#define NWG 256
#define NTHR 256
#define LEAD 8
#define SMEM_BYTES (98304 + 4096 + 1024 + 128 + 32)

// h0[k] at slot k+1 (slot 0 = zeros); h1[t] at slot t+1. 134 MB each.
__device__ __align__(16) unsigned int g_h0[1025LL * 64 * 512];
__device__ __align__(16) unsigned int g_h1[1025LL * 64 * 512];
// xg0 = x @ W0 (no bias): [t][slice(64)][g(2)][row(32)][colw(8)*3] fp32
__device__ __align__(16) float g_xg[1024LL * 64 * 2 * 32 * 24];
// one-time init barrier state (BSS zero; monotone across launches)
__device__ unsigned int g_leaf[8 * 64];
__device__ unsigned int g_root[64];
__device__ unsigned int g_epoch[64];
// per-(slice,wave) step flags; monotone across launches
__device__ __align__(256) unsigned int g_flags[2][2][256];  // [cell][g][slice*4+wv]

__device__ __forceinline__ void f2hilo(float f, unsigned short& hi, unsigned short& lo) {
    __bf16 h = (__bf16)f;
    float  fh = (float)h;
    __bf16 l = (__bf16)(f - fh);
    hi = __builtin_bit_cast(unsigned short, h);
    lo = __builtin_bit_cast(unsigned short, l);
}

__device__ __forceinline__ f32x4 mfma16(bf16x8 a, bf16x8 b, f32x4 c) {
    return __builtin_amdgcn_mfma_f32_16x16x32_bf16(a, b, c, 0, 0, 0);
}

__device__ __forceinline__ void unpack2(uint4v v0, uint4v v1, bf16x8& ah, bf16x8& al) {
    uint4v h, l;
    h.x = __builtin_amdgcn_perm(v0.y, v0.x, 0x07060302u);
    h.y = __builtin_amdgcn_perm(v0.w, v0.z, 0x07060302u);
    h.z = __builtin_amdgcn_perm(v1.y, v1.x, 0x07060302u);
    h.w = __builtin_amdgcn_perm(v1.w, v1.z, 0x07060302u);
    l.x = __builtin_amdgcn_perm(v0.y, v0.x, 0x05040100u);
    l.y = __builtin_amdgcn_perm(v0.w, v0.z, 0x05040100u);
    l.z = __builtin_amdgcn_perm(v1.y, v1.x, 0x05040100u);
    l.w = __builtin_amdgcn_perm(v1.w, v1.z, 0x05040100u);
    ah = __builtin_bit_cast(bf16x8, h);
    al = __builtin_bit_cast(bf16x8, l);
}

// packed-A GEMM pass, register-staged (32 dwordx4 in flight, then compute)
template<int PASS>
__device__ __forceinline__ void gemm_h(
    int ntile, int lane, int lcol, int kch,
    const unsigned int* Ap, const unsigned short* sBhi, const unsigned short* sBlo,
    f32x4& acc_zr, f32x4& acc_o)
{
    uint4v A0[16], A1[16];
    #pragma unroll
    for (int ks = 0; ks < 16; ++ks) {
        const uint4v* p = (const uint4v*)(Ap + ks * 32 + kch * 8);
        A0[ks] = p[0];
        A1[ks] = p[1];
    }
    const bf16x8 bzero = {};
    #pragma unroll
    for (int ks = 0; ks < 16; ++ks) {
        bf16x8 ah, al;
        unpack2(A0[ks], A1[ks], ah, al);
        if (ntile == 0) {
            const int o = PASS * 12288 + ks * 512 + lane * 8;
            bf16x8 bh = *(const bf16x8*)(sBhi + o);
            bf16x8 bl = *(const bf16x8*)(sBlo + o);
            acc_zr = mfma16(ah, bh, acc_zr);
            acc_zr = mfma16(ah, bl, acc_zr);
            acc_zr = mfma16(al, bh, acc_zr);
        } else {
            bf16x8 bh = bzero, bl = bzero;
            if (lcol < 8) {
                const int o = PASS * 12288 + 8192 + ks * 256 + (kch * 8 + lcol) * 8;
                bh = *(const bf16x8*)(sBhi + o);
                bl = *(const bf16x8*)(sBlo + o);
            }
            acc_o = mfma16(ah, bh, acc_o);
            acc_o = mfma16(ah, bl, acc_o);
            acc_o = mfma16(al, bh, acc_o);
        }
    }
}

// float-A GEMM pass for phase 1 (PASS=0 weights), register-staged
__device__ __forceinline__ void gemm_x(
    int ntile, int lane, int lcol, int kch, const float* A,
    const unsigned short* sBhi, const unsigned short* sBlo,
    f32x4& acc_zr, f32x4& acc_xh)
{
    float4 F0[16], F1[16];
    #pragma unroll
    for (int ks = 0; ks < 16; ++ks) {
        const float4* p = (const float4*)(A + ks * 32 + kch * 8);
        F0[ks] = p[0];
        F1[ks] = p[1];
    }
    const bf16x8 bzero = {};
    #pragma unroll
    for (int ks = 0; ks < 16; ++ks) {
        float f[8] = {F0[ks].x, F0[ks].y, F0[ks].z, F0[ks].w,
                      F1[ks].x, F1[ks].y, F1[ks].z, F1[ks].w};
        bf16x8 ah, al;
        #pragma unroll
        for (int i = 0; i < 8; ++i) {
            __bf16 hv = (__bf16)f[i];
            ah[i] = hv;
            al[i] = (__bf16)(f[i] - (float)hv);
        }
        if (ntile == 0) {
            const int o = ks * 512 + lane * 8;
            bf16x8 bh = *(const bf16x8*)(sBhi + o);
            bf16x8 bl = *(const bf16x8*)(sBlo + o);
            acc_zr = mfma16(ah, bh, acc_zr);
            acc_zr = mfma16(ah, bl, acc_zr);
            acc_zr = mfma16(al, bh, acc_zr);
        } else {
            bf16x8 bh = bzero, bl = bzero;
            if (lcol < 8) {
                const int o = 8192 + ks * 256 + (kch * 8 + lcol) * 8;
                bh = *(const bf16x8*)(sBhi + o);
                bl = *(const bf16x8*)(sBlo + o);
            }
            acc_xh = mfma16(ah, bh, acc_xh);
            acc_xh = mfma16(ah, bl, acc_xh);
            acc_xh = mfma16(al, bh, acc_xh);
        }
    }
}

// pack a weight slice into LDS (B-frag layout), bf16 hi/lo (verified)
__device__ __forceinline__ void pack_weights(
    const float* Wm, const float* Um, int c0, int tid,
    unsigned short* sBhi, unsigned short* sBlo)
{
    for (int e = tid; e < 24576; e += NTHR) {
        const int pass = e / 12288;
        const int rem  = e % 12288;
        int j, gcol;
        if (rem < 8192) {
            const int ks = rem >> 9, r2 = rem & 511;
            const int entry = r2 >> 3, i = r2 & 7;
            const int col = entry & 15, kch = entry >> 4;
            j = ks * 32 + kch * 8 + i;
            gcol = (col < 8) ? (c0 + col) : (512 + c0 + col - 8);
        } else {
            const int r2 = rem - 8192;
            const int ks = r2 >> 8, r3 = r2 & 255;
            const int entry = r3 >> 3, i = r3 & 7;
            const int col = entry & 7, kch = entry >> 3;
            j = ks * 32 + kch * 8 + i;
            gcol = 1024 + c0 + col;
        }
        const float v = (pass ? Um : Wm)[j * 1536 + gcol];
        f2hilo(v, sBhi[e], sBlo[e]);
    }
}

// wave0 polls all 256 (slice,wave) flags (2x u64 per lane); tid0 additionally
// checks the backpressure flag. One __syncthreads release.
__device__ __forceinline__ void wait_all(const unsigned int* F, unsigned int target,
                                         const unsigned int* bpF, unsigned int bptarget,
                                         int tid)
{
    if (tid < 64) {
        const unsigned long long* p = (const unsigned long long*)(F + tid * 4);
        for (;;) {
            unsigned long long v01 = __hip_atomic_load(p,     __ATOMIC_RELAXED,
                                                       __HIP_MEMORY_SCOPE_AGENT);
            unsigned long long v23 = __hip_atomic_load(p + 1, __ATOMIC_RELAXED,
                                                       __HIP_MEMORY_SCOPE_AGENT);
            bool ok = (int)((unsigned int)v01 - target) >= 0
                   && (int)((unsigned int)(v01 >> 32) - target) >= 0
                   && (int)((unsigned int)v23 - target) >= 0
                   && (int)((unsigned int)(v23 >> 32) - target) >= 0;
            if (bpF != nullptr && tid == 0) {
                unsigned int b = __hip_atomic_load(bpF, __ATOMIC_RELAXED,
                                                   __HIP_MEMORY_SCOPE_AGENT);
                ok = ok && ((int)(b - bptarget) >= 0);
            }
            if (__all(ok)) break;
            __builtin_amdgcn_s_sleep(1);
        }
    }
    __syncthreads();
}

// epilogue: accs (+opt xg) -> gates -> hn; publish h + per-wave flag.
// ONE internal __syncthreads; the caller's next wait_all provides the
// read->write hazard barrier for sAcc across iterations.
__device__ __forceinline__ void epilogue_pub(
    int tid, int mtile, int ntile, int lane, int lcol,
    const f32x4& acc_zr, const f32x4& acc_xh, const f32x4& acc_hh,
    float* sAcc, const float* sBias, float& hprev,
    bool useXg, float xgz, float xgr, float xgh,
    unsigned int* hdst, unsigned int* flagp, unsigned int flagval, float* outp)
{
    const int drow = mtile * 16 + (lane >> 4) * 4;
    if (ntile == 0) {
        #pragma unroll
        for (int r2 = 0; r2 < 4; ++r2) sAcc[(drow + r2) * 16 + lcol] = acc_zr[r2];
    } else if (lcol < 8) {
        #pragma unroll
        for (int r2 = 0; r2 < 4; ++r2) {
            if (!useXg) sAcc[512 + (drow + r2) * 8 + lcol] = acc_xh[r2];
            sAcc[768 + (drow + r2) * 8 + lcol] = acc_hh[r2];
        }
    }
    __syncthreads();
    const int ml  = tid >> 3;
    const int col = tid & 7;
    float zp = sAcc[ml * 16 + col]     + sBias[col];
    float rp = sAcc[ml * 16 + 8 + col] + sBias[8 + col];
    if (useXg) { zp += xgz; rp += xgr; }
    const float z = 1.f / (1.f + __expf(-zp));
    const float r = 1.f / (1.f + __expf(-rp));
    const float xh = (useXg ? xgh : sAcc[512 + ml * 8 + col]) + sBias[16 + col];
    const float hh = sAcc[768 + ml * 8 + col] + sBias[24 + col];
    const float ct = tanhf(xh + r * hh);
    const float hn = z * hprev + (1.f - z) * ct;
    hprev = hn;
    unsigned short hi_, lo_;
    f2hilo(hn, hi_, lo_);
    const unsigned int pk = ((unsigned int)hi_ << 16) | (unsigned int)lo_;
    __hip_atomic_store(hdst, pk, __ATOMIC_RELAXED, __HIP_MEMORY_SCOPE_AGENT);
    if (outp) *outp = hn;
    // per-wave drain of own h stores, then lane0 publishes this wave's flag
    asm volatile("s_waitcnt vmcnt(0)" ::: "memory");
    if ((tid & 63) == 0)
        __hip_atomic_store(flagp, flagval, __ATOMIC_RELAXED, __HIP_MEMORY_SCOPE_AGENT);
}

__global__ void __launch_bounds__(NTHR, 1) gru_persistent(
    const float* __restrict__ x,  const float* __restrict__ W0,
    const float* __restrict__ U0, const float* __restrict__ b0,
    const float* __restrict__ W1, const float* __restrict__ U1,
    const float* __restrict__ b1, float* __restrict__ out)
{
    extern __shared__ char smem[];
    unsigned short* sBhi = (unsigned short*)smem;
    unsigned short* sBlo = sBhi + 24576;
    float* sAcc   = (float*)(smem + 98304);
    float* sBias  = sAcc + 1024 + 256;
    unsigned int* sE0 = (unsigned int*)(sBias + 32);

    const int wg    = blockIdx.x;
    const int g     = wg >> 7;
    const int cell  = (wg >> 6) & 1;
    const int slice = wg & 63;
    const int c0    = slice * 8;
    const int tid   = threadIdx.x;

    // kill stale L1/L2 lines from a previous launch
    __builtin_amdgcn_fence(__ATOMIC_ACQUIRE, "agent");

    if (tid == 0)
        sE0[0] = __hip_atomic_load(&g_epoch[0], __ATOMIC_RELAXED, __HIP_MEMORY_SCOPE_AGENT);

    // zero own region of slot 0 (h[-1] = 0)
    {
        const int mlz = tid >> 3, colz = tid & 7;
        unsigned int* dst = (cell ? g_h1 : g_h0)
                          + (long long)(g * 32 + mlz) * 512 + (c0 + colz);
        __hip_atomic_store(dst, 0u, __ATOMIC_RELAXED, __HIP_MEMORY_SCOPE_AGENT);
    }

    // phase-1 weights: W0 -> pass0 region, U0 -> pass1 region (ALL WGs)
    pack_weights(W0, U0, c0, tid, sBhi, sBlo);

    // biases for own cell (used only in phase 2)
    {
        const float* b = cell ? b1 : b0;
        if (tid < 32) {
            const int col = tid & 7, sec = tid >> 3;
            float v;
            if (sec == 0)      v = b[c0 + col] + b[1536 + c0 + col];
            else if (sec == 1) v = b[512 + c0 + col] + b[1536 + 512 + c0 + col];
            else if (sec == 2) v = b[1024 + c0 + col];
            else               v = b[1536 + 1024 + c0 + col];
            sBias[tid] = v;
        }
    }
    __syncthreads();
    const unsigned int E0 = sE0[0];
    const unsigned int EB = (E0 + 1u) << 10;   // epoch-extended flag base

    const int lane  = tid & 63;
    const int mtile = (tid >> 6) & 1;
    const int ntile = tid >> 7;
    const int lcol  = lane & 15;
    const int kch   = lane >> 4;
    const int arow  = g * 32 + mtile * 16 + lcol;
    const int ml    = tid >> 3;
    const int colw  = tid & 7;

    // ---- PHASE 1: xg = x @ W0 for t in quarter q, all b ----
    {
        const int q = wg >> 6;   // 0..3 -> t in [q*256, q*256+256)
        for (int bb = 0; bb < 64; ++bb) {
            for (int j = 0; j < 8; ++j) {
                const int t0 = q * 256 + j * 32;
                f32x4 acc_zr = {0.f, 0.f, 0.f, 0.f};
                f32x4 acc_xh = {0.f, 0.f, 0.f, 0.f};
                const float* A = x + ((long long)bb * 1024 + t0 + mtile * 16 + lcol) * 512;
                gemm_x(ntile, lane, lcol, kch, A, sBhi, sBlo, acc_zr, acc_xh);
                __syncthreads();   // prior iter's sAcc reads done
                const int drow = mtile * 16 + (lane >> 4) * 4;
                if (ntile == 0) {
                    #pragma unroll
                    for (int r2 = 0; r2 < 4; ++r2) sAcc[(drow + r2) * 16 + lcol] = acc_zr[r2];
                } else if (lcol < 8) {
                    #pragma unroll
                    for (int r2 = 0; r2 < 4; ++r2) sAcc[512 + (drow + r2) * 8 + lcol] = acc_xh[r2];
                }
                __syncthreads();
                const float zv = sAcc[ml * 16 + colw];
                const float rv = sAcc[ml * 16 + 8 + colw];
                const float hv = sAcc[512 + ml * 8 + colw];
                // gate-contiguous: [t][slice][g=bb>>5][row=bb&31][colw*3 + gate]
                float* dst = g_xg + (long long)(t0 + ml) * 98304
                           + slice * 1536 + (bb >> 5) * 768 + (bb & 31) * 24 + colw * 3;
                __hip_atomic_store((unsigned int*)dst,
                    __builtin_bit_cast(unsigned int, zv), __ATOMIC_RELAXED, __HIP_MEMORY_SCOPE_AGENT);
                __hip_atomic_store((unsigned int*)(dst + 1),
                    __builtin_bit_cast(unsigned int, rv), __ATOMIC_RELAXED, __HIP_MEMORY_SCOPE_AGENT);
                __hip_atomic_store((unsigned int*)(dst + 2),
                    __builtin_bit_cast(unsigned int, hv), __ATOMIC_RELAXED, __HIP_MEMORY_SCOPE_AGENT);
            }
        }
    }
    __syncthreads();   // per-wave vmcnt(0) drain before grid barrier

    // ---- grid barrier (xg + slot0 zeros now safe everywhere) ----
    {
        const unsigned int target = E0 + 1u;
        if (tid == 0) {
            asm volatile("s_waitcnt vmcnt(0)" ::: "memory");
            unsigned int o = __hip_atomic_fetch_add(&g_leaf[(wg & 7) * 64], 1u,
                                __ATOMIC_RELAXED, __HIP_MEMORY_SCOPE_AGENT);
            if (o == 32u * target - 1u) {
                unsigned int r = __hip_atomic_fetch_add(&g_root[0], 1u,
                                    __ATOMIC_RELAXED, __HIP_MEMORY_SCOPE_AGENT);
                if (r == 8u * target - 1u)
                    __hip_atomic_store(&g_epoch[0], target,
                                       __ATOMIC_RELAXED, __HIP_MEMORY_SCOPE_AGENT);
            }
        }
        while ((int)(__hip_atomic_load(&g_epoch[0], __ATOMIC_RELAXED,
                                       __HIP_MEMORY_SCOPE_AGENT) - target) < 0)
            __builtin_amdgcn_s_sleep(1);
        asm volatile("" ::: "memory");
        __syncthreads();
    }

    // ---- repack for phase 2: cell1 needs W1/U1 (cell0 keeps U0 in pass1) ----
    if (cell == 1) {
        pack_weights(W1, U1, c0, tid, sBhi, sBlo);
        __syncthreads();
    }

    float hprev = 0.f;

    if (cell == 0) {
        unsigned int* const ownF = &g_flags[0][g][0];
        unsigned int* const myFp = &g_flags[0][g][slice * 4 + (tid >> 6)];
        const unsigned int* bpFp = &g_flags[1][g][slice * 4];   // counterpart wave0
        const float* xgb = g_xg + slice * 1536 + g * 768 + ml * 24 + colw * 3;
        // preload xg[0]
        float xgz = xgb[0], xgr = xgb[1], xgh = xgb[2];
        for (int k = 0; k < T_STEPS; ++k) {
            if (k > 0)
                wait_all(ownF, EB + (unsigned int)k,
                         (k > LEAD) ? bpFp : nullptr, EB + (unsigned int)(k - LEAD), tid);
            // prefetch next step's xg (consumed next iteration; lands during pass)
            const int kn = (k + 1 < T_STEPS) ? k + 1 : k;
            const float* xgn = xgb + (long long)kn * 98304;
            const float nz = xgn[0], nr = xgn[1], nh = xgn[2];

            f32x4 acc_zr = {0.f, 0.f, 0.f, 0.f};
            f32x4 acc_hh = {0.f, 0.f, 0.f, 0.f};
            const unsigned int* A1p = g_h0 + (long long)k * (64 * 512) + arow * 512;
            gemm_h<1>(ntile, lane, lcol, kch, A1p, sBhi, sBlo, acc_zr, acc_hh);

            unsigned int* hdst = g_h0 + (long long)(k + 1) * (64 * 512)
                               + (long long)(g * 32 + ml) * 512 + (c0 + colw);
            epilogue_pub(tid, mtile, ntile, lane, lcol,
                         acc_zr, acc_zr /*xh unused*/, acc_hh,
                         sAcc, sBias, hprev, true, xgz, xgr, xgh,
                         hdst, myFp, EB + (unsigned int)(k + 1), nullptr);
            xgz = nz; xgr = nr; xgh = nh;
        }
    } else {
        unsigned int* const ownF = &g_flags[1][g][0];
        const unsigned int* upF  = &g_flags[0][g][0];
        unsigned int* const myFp = &g_flags[1][g][slice * 4 + (tid >> 6)];
        for (int t = 0; t < T_STEPS; ++t) {
            // upstream h0[t] (cell0 runs ahead -> normally satisfied)
            wait_all(upF, EB + (unsigned int)(t + 1), nullptr, 0u, tid);

            f32x4 acc_zr = {0.f, 0.f, 0.f, 0.f};
            f32x4 acc_xh = {0.f, 0.f, 0.f, 0.f};
            f32x4 acc_hh = {0.f, 0.f, 0.f, 0.f};

            // input-side pass FIRST (doesn't need h1[t-1]; overlaps own-wait lag)
            const unsigned int* A0p = g_h0 + (long long)(t + 1) * (64 * 512) + arow * 512;
            gemm_h<0>(ntile, lane, lcol, kch, A0p, sBhi, sBlo, acc_zr, acc_xh);

            if (t > 0) wait_all(ownF, EB + (unsigned int)t, nullptr, 0u, tid);

            const unsigned int* A1p = g_h1 + (long long)t * (64 * 512) + arow * 512;
            gemm_h<1>(ntile, lane, lcol, kch, A1p, sBhi, sBlo, acc_zr, acc_hh);

            unsigned int* hdst = g_h1 + (long long)(t + 1) * (64 * 512)
                               + (long long)(g * 32 + ml) * 512 + (c0 + colw);
            float* outp = (t == T_STEPS - 1)
                        ? &out[(g * 32 + ml) * 512 + (c0 + colw)] : nullptr;
            epilogue_pub(tid, mtile, ntile, lane, lcol,
                         acc_zr, acc_xh, acc_hh,
                         sAcc, sBias, hprev, false, 0.f, 0.f, 0.f,
                         hdst, myFp, EB + (unsigned int)(t + 1), outp);
        }
    }
}

extern "C" void kernel_launch(void* const* d_in, const int* in_sizes, int n_in,
                              void* d_out, int out_size, void* d_ws, size_t ws_size,
                              hipStream_t stream) {
    (void)in_sizes; (void)n_in; (void)d_ws; (void)ws_size; (void)out_size;
    const float* x  = (const float*)d_in[0];
    const float* W0 = (const float*)d_in[1];
    const float* U0 = (const float*)d_in[2];
    const float* b0 = (const float*)d_in[3];
    const float* W1 = (const float*)d_in[4];
    const float* U1 = (const float*)d_in[5];
    const float* b1 = (const float*)d_in[6];
    float* out = (float*)d_out;

    (void)hipFuncSetAttribute((const void*)gru_persistent,
                              hipFuncAttributeMaxDynamicSharedMemorySize, SMEM_BYTES);
    void* args[] = {&x, &W0, &U0, &b0, &W1, &U1, &b1, &out};
    hipError_t e = hipLaunchCooperativeKernel((const void*)gru_persistent,
                                              dim3(NWG), dim3(NTHR),
                                              args, SMEM_BYTES, stream);
    if (e != hipSuccess) {
        gru_persistent<<<dim3(NWG), dim3(NTHR), SMEM_BYTES, stream>>>(
            x, W0, U0, b0, W1, U1, b1, out);
    }
}

// Round 5
// 13122.015 us; speedup vs baseline: 1.2087x; 1.0068x over previous
//
#include <hip/hip_runtime.h>

// ---------------------------------------------------------------------------
// 2-layer GRU (Keras reset_after=true), B=64, T=1024, D=U=512.
// Round-6 = round-5 STRUCTURE + round-3 (proven) SYNC MECHANISM.
//  A/B rationale: rounds 4-5 replaced the single-word counter sync with
//  256-flag vector polling (16 lines x 64 lanes per poll) -> multi-TB/s of
//  redundant L3 poll traffic, contention collapse (53ms outliers). Total MFMA
//  time is constant across rounds => period is pure sync/latency. This round
//  keeps the good structure (xg precompute, ONE gemm pass per cell on the
//  serial chain, backpressure) and reverts sync to: per-clique single-word
//  counters, tid0-only fetch_add producers, tid0-only scalar poll consumers.
//  Refinements: cached last-seen counter values skip the cross/backpressure
//  polls when already satisfied (zero L3 traffic in steady state).
//  (resubmission: previous round failed on container infra, no kernel data)
// ---------------------------------------------------------------------------

typedef __bf16 bf16x8 __attribute__((ext_vector_type(8)));
typedef float  f32x4  __attribute__((ext_vector_type(4)));
typedef unsigned int uint4v __attribute__((ext_vector_type(4)));

#define T_STEPS 1024
#define NWG 256
#define NTHR 256
#define LEAD 8
#define SMEM_BYTES (98304 + 4096 + 1024 + 128 + 32)

// h0[k] at slot k+1 (slot 0 = zeros); h1[t] at slot t+1. 134 MB each.
__device__ __align__(16) unsigned int g_h0[1025LL * 64 * 512];
__device__ __align__(16) unsigned int g_h1[1025LL * 64 * 512];
// xg0 = x @ W0 (no bias): [t][slice(64)][g(2)][row(32)][colw(8)*3] fp32
__device__ __align__(16) float g_xg[1024LL * 64 * 2 * 32 * 24];
// one-time init barrier state (BSS zero; monotone across launches)
__device__ unsigned int g_leaf[8 * 64];
__device__ unsigned int g_root[64];
__device__ unsigned int g_epoch[64];
// per-clique step counters, each on its own 256B line; monotone across launches
__device__ __align__(256) unsigned int g_cnt[2][2][64];   // [cell][g]: own-clique
__device__ __align__(256) unsigned int g_cntx[2][64];     // [g]: cell0 progress

__device__ __forceinline__ void f2hilo(float f, unsigned short& hi, unsigned short& lo) {
    __bf16 h = (__bf16)f;
    float  fh = (float)h;
    __bf16 l = (__bf16)(f - fh);
    hi = __builtin_bit_cast(unsigned short, h);
    lo = __builtin_bit_cast(unsigned short, l);
}

__device__ __forceinline__ f32x4 mfma16(bf16x8 a, bf16x8 b, f32x4 c) {
    return __builtin_amdgcn_mfma_f32_16x16x32_bf16(a, b, c, 0, 0, 0);
}

__device__ __forceinline__ void unpack2(uint4v v0, uint4v v1, bf16x8& ah, bf16x8& al) {
    uint4v h, l;
    h.x = __builtin_amdgcn_perm(v0.y, v0.x, 0x07060302u);
    h.y = __builtin_amdgcn_perm(v0.w, v0.z, 0x07060302u);
    h.z = __builtin_amdgcn_perm(v1.y, v1.x, 0x07060302u);
    h.w = __builtin_amdgcn_perm(v1.w, v1.z, 0x07060302u);
    l.x = __builtin_amdgcn_perm(v0.y, v0.x, 0x05040100u);
    l.y = __builtin_amdgcn_perm(v0.w, v0.z, 0x05040100u);
    l.z = __builtin_amdgcn_perm(v1.y, v1.x, 0x05040100u);
    l.w = __builtin_amdgcn_perm(v1.w, v1.z, 0x05040100u);
    ah = __builtin_bit_cast(bf16x8, h);
    al = __builtin_bit_cast(bf16x8, l);
}

// packed-A GEMM pass, register-staged (32 dwordx4 in flight, then compute)
template<int PASS>
__device__ __forceinline__ void gemm_h(
    int ntile, int lane, int lcol, int kch,
    const unsigned int* Ap, const unsigned short* sBhi, const unsigned short* sBlo,
    f32x4& acc_zr, f32x4& acc_o)
{
    uint4v A0[16], A1[16];
    #pragma unroll
    for (int ks = 0; ks < 16; ++ks) {
        const uint4v* p = (const uint4v*)(Ap + ks * 32 + kch * 8);
        A0[ks] = p[0];
        A1[ks] = p[1];
    }
    const bf16x8 bzero = {};
    #pragma unroll
    for (int ks = 0; ks < 16; ++ks) {
        bf16x8 ah, al;
        unpack2(A0[ks], A1[ks], ah, al);
        if (ntile == 0) {
            const int o = PASS * 12288 + ks * 512 + lane * 8;
            bf16x8 bh = *(const bf16x8*)(sBhi + o);
            bf16x8 bl = *(const bf16x8*)(sBlo + o);
            acc_zr = mfma16(ah, bh, acc_zr);
            acc_zr = mfma16(ah, bl, acc_zr);
            acc_zr = mfma16(al, bh, acc_zr);
        } else {
            bf16x8 bh = bzero, bl = bzero;
            if (lcol < 8) {
                const int o = PASS * 12288 + 8192 + ks * 256 + (kch * 8 + lcol) * 8;
                bh = *(const bf16x8*)(sBhi + o);
                bl = *(const bf16x8*)(sBlo + o);
            }
            acc_o = mfma16(ah, bh, acc_o);
            acc_o = mfma16(ah, bl, acc_o);
            acc_o = mfma16(al, bh, acc_o);
        }
    }
}

// float-A GEMM pass for phase 1 (PASS=0 weights), register-staged
__device__ __forceinline__ void gemm_x(
    int ntile, int lane, int lcol, int kch, const float* A,
    const unsigned short* sBhi, const unsigned short* sBlo,
    f32x4& acc_zr, f32x4& acc_xh)
{
    float4 F0[16], F1[16];
    #pragma unroll
    for (int ks = 0; ks < 16; ++ks) {
        const float4* p = (const float4*)(A + ks * 32 + kch * 8);
        F0[ks] = p[0];
        F1[ks] = p[1];
    }
    const bf16x8 bzero = {};
    #pragma unroll
    for (int ks = 0; ks < 16; ++ks) {
        float f[8] = {F0[ks].x, F0[ks].y, F0[ks].z, F0[ks].w,
                      F1[ks].x, F1[ks].y, F1[ks].z, F1[ks].w};
        bf16x8 ah, al;
        #pragma unroll
        for (int i = 0; i < 8; ++i) {
            __bf16 hv = (__bf16)f[i];
            ah[i] = hv;
            al[i] = (__bf16)(f[i] - (float)hv);
        }
        if (ntile == 0) {
            const int o = ks * 512 + lane * 8;
            bf16x8 bh = *(const bf16x8*)(sBhi + o);
            bf16x8 bl = *(const bf16x8*)(sBlo + o);
            acc_zr = mfma16(ah, bh, acc_zr);
            acc_zr = mfma16(ah, bl, acc_zr);
            acc_zr = mfma16(al, bh, acc_zr);
        } else {
            bf16x8 bh = bzero, bl = bzero;
            if (lcol < 8) {
                const int o = 8192 + ks * 256 + (kch * 8 + lcol) * 8;
                bh = *(const bf16x8*)(sBhi + o);
                bl = *(const bf16x8*)(sBlo + o);
            }
            acc_xh = mfma16(ah, bh, acc_xh);
            acc_xh = mfma16(ah, bl, acc_xh);
            acc_xh = mfma16(al, bh, acc_xh);
        }
    }
}

// pack a weight slice into LDS (B-frag layout), bf16 hi/lo (verified)
__device__ __forceinline__ void pack_weights(
    const float* Wm, const float* Um, int c0, int tid,
    unsigned short* sBhi, unsigned short* sBlo)
{
    for (int e = tid; e < 24576; e += NTHR) {
        const int pass = e / 12288;
        const int rem  = e % 12288;
        int j, gcol;
        if (rem < 8192) {
            const int ks = rem >> 9, r2 = rem & 511;
            const int entry = r2 >> 3, i = r2 & 7;
            const int col = entry & 15, kch = entry >> 4;
            j = ks * 32 + kch * 8 + i;
            gcol = (col < 8) ? (c0 + col) : (512 + c0 + col - 8);
        } else {
            const int r2 = rem - 8192;
            const int ks = r2 >> 8, r3 = r2 & 255;
            const int entry = r3 >> 3, i = r3 & 7;
            const int col = entry & 7, kch = entry >> 3;
            j = ks * 32 + kch * 8 + i;
            gcol = 1024 + c0 + col;
        }
        const float v = (pass ? Um : Wm)[j * 1536 + gcol];
        f2hilo(v, sBhi[e], sBlo[e]);
    }
}

// tid0-only scalar poll with backoff; returns last value seen (tid0 only)
__device__ __forceinline__ unsigned int spin_until(unsigned int* C, unsigned int target) {
    int spins = 0;
    for (;;) {
        unsigned int v = __hip_atomic_load(C, __ATOMIC_RELAXED, __HIP_MEMORY_SCOPE_AGENT);
        if ((int)(v - target) >= 0) return v;
        if (spins < 6) __builtin_amdgcn_s_sleep(1);
        else           __builtin_amdgcn_s_sleep(4);
        ++spins;
    }
}

// epilogue: accs (+opt xg) -> gates -> hn (per thread ml,col)
__device__ __forceinline__ float epilogue_hn(
    int tid, int mtile, int ntile, int lane, int lcol,
    const f32x4& acc_zr, const f32x4& acc_xh, const f32x4& acc_hh,
    float* sAcc, const float* sBias, float hp,
    bool useXg, float xgz, float xgr, float xgh)
{
    const int drow = mtile * 16 + (lane >> 4) * 4;
    if (ntile == 0) {
        #pragma unroll
        for (int r2 = 0; r2 < 4; ++r2) sAcc[(drow + r2) * 16 + lcol] = acc_zr[r2];
    } else if (lcol < 8) {
        #pragma unroll
        for (int r2 = 0; r2 < 4; ++r2) {
            if (!useXg) sAcc[512 + (drow + r2) * 8 + lcol] = acc_xh[r2];
            sAcc[768 + (drow + r2) * 8 + lcol] = acc_hh[r2];
        }
    }
    __syncthreads();
    const int ml  = tid >> 3;
    const int col = tid & 7;
    float zp = sAcc[ml * 16 + col]     + sBias[col];
    float rp = sAcc[ml * 16 + 8 + col] + sBias[8 + col];
    if (useXg) { zp += xgz; rp += xgr; }
    const float z = 1.f / (1.f + __expf(-zp));
    const float r = 1.f / (1.f + __expf(-rp));
    const float xh = (useXg ? xgh : sAcc[512 + ml * 8 + col]) + sBias[16 + col];
    const float hh = sAcc[768 + ml * 8 + col] + sBias[24 + col];
    const float ct = tanhf(xh + r * hh);
    return z * hp + (1.f - z) * ct;
}

__global__ void __launch_bounds__(NTHR, 1) gru_persistent(
    const float* __restrict__ x,  const float* __restrict__ W0,
    const float* __restrict__ U0, const float* __restrict__ b0,
    const float* __restrict__ W1, const float* __restrict__ U1,
    const float* __restrict__ b1, float* __restrict__ out)
{
    extern __shared__ char smem[];
    unsigned short* sBhi = (unsigned short*)smem;
    unsigned short* sBlo = sBhi + 24576;
    float* sAcc   = (float*)(smem + 98304);
    float* sBias  = sAcc + 1024 + 256;
    unsigned int* sE0 = (unsigned int*)(sBias + 32);

    const int wg    = blockIdx.x;
    const int g     = wg >> 7;
    const int cell  = (wg >> 6) & 1;
    const int slice = wg & 63;
    const int c0    = slice * 8;
    const int tid   = threadIdx.x;

    // kill stale L1/L2 lines from a previous launch
    __builtin_amdgcn_fence(__ATOMIC_ACQUIRE, "agent");

    // counter bases: read before the init grid-barrier (no adds until after it)
    if (tid == 0) {
        sE0[0] = __hip_atomic_load(&g_epoch[0], __ATOMIC_RELAXED, __HIP_MEMORY_SCOPE_AGENT);
        sE0[1] = __hip_atomic_load(&g_cnt[cell][g][0], __ATOMIC_RELAXED, __HIP_MEMORY_SCOPE_AGENT);
        sE0[2] = __hip_atomic_load(&g_cntx[g][0], __ATOMIC_RELAXED, __HIP_MEMORY_SCOPE_AGENT);
        sE0[3] = __hip_atomic_load(&g_cnt[1][g][0], __ATOMIC_RELAXED, __HIP_MEMORY_SCOPE_AGENT);
    }

    // zero own region of slot 0 (h[-1] = 0)
    {
        const int mlz = tid >> 3, colz = tid & 7;
        unsigned int* dst = (cell ? g_h1 : g_h0)
                          + (long long)(g * 32 + mlz) * 512 + (c0 + colz);
        __hip_atomic_store(dst, 0u, __ATOMIC_RELAXED, __HIP_MEMORY_SCOPE_AGENT);
    }

    // phase-1 weights: W0 -> pass0 region, U0 -> pass1 region (ALL WGs)
    pack_weights(W0, U0, c0, tid, sBhi, sBlo);

    // biases for own cell (used only in phase 2)
    {
        const float* b = cell ? b1 : b0;
        if (tid < 32) {
            const int col = tid & 7, sec = tid >> 3;
            float v;
            if (sec == 0)      v = b[c0 + col] + b[1536 + c0 + col];
            else if (sec == 1) v = b[512 + c0 + col] + b[1536 + 512 + c0 + col];
            else if (sec == 2) v = b[1024 + c0 + col];
            else               v = b[1536 + 1024 + c0 + col];
            sBias[tid] = v;
        }
    }
    __syncthreads();
    const unsigned int E0     = sE0[0];
    const unsigned int Cown   = sE0[1];
    const unsigned int Ccross = sE0[2];
    const unsigned int C1     = sE0[3];

    const int lane  = tid & 63;
    const int mtile = (tid >> 6) & 1;
    const int ntile = tid >> 7;
    const int lcol  = lane & 15;
    const int kch   = lane >> 4;
    const int arow  = g * 32 + mtile * 16 + lcol;
    const int ml    = tid >> 3;
    const int colw  = tid & 7;

    // ---- PHASE 1: xg = x @ W0 for t in quarter q, all b ----
    {
        const int q = wg >> 6;   // 0..3 -> t in [q*256, q*256+256)
        for (int bb = 0; bb < 64; ++bb) {
            for (int j = 0; j < 8; ++j) {
                const int t0 = q * 256 + j * 32;
                f32x4 acc_zr = {0.f, 0.f, 0.f, 0.f};
                f32x4 acc_xh = {0.f, 0.f, 0.f, 0.f};
                const float* A = x + ((long long)bb * 1024 + t0 + mtile * 16 + lcol) * 512;
                gemm_x(ntile, lane, lcol, kch, A, sBhi, sBlo, acc_zr, acc_xh);
                __syncthreads();   // prior iter's sAcc reads done
                const int drow = mtile * 16 + (lane >> 4) * 4;
                if (ntile == 0) {
                    #pragma unroll
                    for (int r2 = 0; r2 < 4; ++r2) sAcc[(drow + r2) * 16 + lcol] = acc_zr[r2];
                } else if (lcol < 8) {
                    #pragma unroll
                    for (int r2 = 0; r2 < 4; ++r2) sAcc[512 + (drow + r2) * 8 + lcol] = acc_xh[r2];
                }
                __syncthreads();
                const float zv = sAcc[ml * 16 + colw];
                const float rv = sAcc[ml * 16 + 8 + colw];
                const float hv = sAcc[512 + ml * 8 + colw];
                // gate-contiguous: [t][slice][g=bb>>5][row=bb&31][colw*3 + gate]
                float* dst = g_xg + (long long)(t0 + ml) * 98304
                           + slice * 1536 + (bb >> 5) * 768 + (bb & 31) * 24 + colw * 3;
                __hip_atomic_store((unsigned int*)dst,
                    __builtin_bit_cast(unsigned int, zv), __ATOMIC_RELAXED, __HIP_MEMORY_SCOPE_AGENT);
                __hip_atomic_store((unsigned int*)(dst + 1),
                    __builtin_bit_cast(unsigned int, rv), __ATOMIC_RELAXED, __HIP_MEMORY_SCOPE_AGENT);
                __hip_atomic_store((unsigned int*)(dst + 2),
                    __builtin_bit_cast(unsigned int, hv), __ATOMIC_RELAXED, __HIP_MEMORY_SCOPE_AGENT);
            }
        }
    }
    __syncthreads();   // per-wave vmcnt(0) drain before grid barrier

    // ---- grid barrier (xg + slot0 zeros now safe everywhere) ----
    {
        const unsigned int target = E0 + 1u;
        if (tid == 0) {
            asm volatile("s_waitcnt vmcnt(0)" ::: "memory");
            unsigned int o = __hip_atomic_fetch_add(&g_leaf[(wg & 7) * 64], 1u,
                                __ATOMIC_RELAXED, __HIP_MEMORY_SCOPE_AGENT);
            if (o == 32u * target - 1u) {
                unsigned int r = __hip_atomic_fetch_add(&g_root[0], 1u,
                                    __ATOMIC_RELAXED, __HIP_MEMORY_SCOPE_AGENT);
                if (r == 8u * target - 1u)
                    __hip_atomic_store(&g_epoch[0], target,
                                       __ATOMIC_RELAXED, __HIP_MEMORY_SCOPE_AGENT);
            }
        }
        while ((int)(__hip_atomic_load(&g_epoch[0], __ATOMIC_RELAXED,
                                       __HIP_MEMORY_SCOPE_AGENT) - target) < 0)
            __builtin_amdgcn_s_sleep(1);
        asm volatile("" ::: "memory");
        __syncthreads();
    }

    // ---- repack for phase 2: cell1 needs W1/U1 (cell0 keeps U0 in pass1) ----
    if (cell == 1) {
        pack_weights(W1, U1, c0, tid, sBhi, sBlo);
        __syncthreads();
    }

    float hprev = 0.f;

    if (cell == 0) {
        unsigned int* const cnt  = &g_cnt[0][g][0];
        unsigned int* const cntx = &g_cntx[g][0];
        unsigned int* const cnt1 = &g_cnt[1][g][0];
        const float* xgb = g_xg + slice * 1536 + g * 768 + ml * 24 + colw * 3;
        float xgz = xgb[0], xgr = xgb[1], xgh = xgb[2];
        unsigned int c1seen = C1;   // meaningful on tid0 only
        for (int k = 0; k < T_STEPS; ++k) {
            if (k > 0) {
                if (tid == 0) {
                    spin_until(cnt, Cown + 64u * (unsigned int)k);
                    if (k > LEAD) {
                        const unsigned int bt = C1 + 64u * (unsigned int)(k - LEAD);
                        if ((int)(c1seen - bt) < 0)
                            c1seen = spin_until(cnt1, bt);
                    }
                }
                __syncthreads();
            }
            // prefetch next step's xg (consumed next iteration)
            const int kn = (k + 1 < T_STEPS) ? k + 1 : k;
            const float* xgn = xgb + (long long)kn * 98304;
            const float nz = xgn[0], nr = xgn[1], nh = xgn[2];

            f32x4 acc_zr = {0.f, 0.f, 0.f, 0.f};
            f32x4 acc_hh = {0.f, 0.f, 0.f, 0.f};
            const unsigned int* A1p = g_h0 + (long long)k * (64 * 512) + arow * 512;
            gemm_h<1>(ntile, lane, lcol, kch, A1p, sBhi, sBlo, acc_zr, acc_hh);

            const float hn = epilogue_hn(tid, mtile, ntile, lane, lcol,
                                         acc_zr, acc_zr /*xh unused*/, acc_hh,
                                         sAcc, sBias, hprev, true, xgz, xgr, xgh);
            hprev = hn;
            {
                unsigned short hi_, lo_;
                f2hilo(hn, hi_, lo_);
                const unsigned int pk = ((unsigned int)hi_ << 16) | (unsigned int)lo_;
                unsigned int* dst = g_h0 + (long long)(k + 1) * (64 * 512)
                                  + (long long)(g * 32 + ml) * 512 + (c0 + colw);
                __hip_atomic_store(dst, pk, __ATOMIC_RELAXED, __HIP_MEMORY_SCOPE_AGENT);
            }
            __syncthreads();   // per-wave vmcnt(0) drain before counter add
            if (tid == 0) {
                __hip_atomic_fetch_add(cnt,  1u, __ATOMIC_RELAXED, __HIP_MEMORY_SCOPE_AGENT);
                __hip_atomic_fetch_add(cntx, 1u, __ATOMIC_RELAXED, __HIP_MEMORY_SCOPE_AGENT);
            }
            xgz = nz; xgr = nr; xgh = nh;
        }
    } else {
        unsigned int* const cnt  = &g_cnt[1][g][0];
        unsigned int* const cntU = &g_cntx[g][0];
        unsigned int upseen = Ccross;   // meaningful on tid0 only
        for (int t = 0; t < T_STEPS; ++t) {
            // upstream h0[t] (cell0 runs LEAD ahead -> cached check usually skips)
            if (tid == 0) {
                const unsigned int ut = Ccross + 64u * (unsigned int)(t + 1);
                if ((int)(upseen - ut) < 0)
                    upseen = spin_until(cntU, ut);
            }
            __syncthreads();

            f32x4 acc_zr = {0.f, 0.f, 0.f, 0.f};
            f32x4 acc_xh = {0.f, 0.f, 0.f, 0.f};
            f32x4 acc_hh = {0.f, 0.f, 0.f, 0.f};

            // input-side pass FIRST (needs only h0[t]; off the own-recurrence chain)
            const unsigned int* A0p = g_h0 + (long long)(t + 1) * (64 * 512) + arow * 512;
            gemm_h<0>(ntile, lane, lcol, kch, A0p, sBhi, sBlo, acc_zr, acc_xh);

            if (t > 0) {
                if (tid == 0) spin_until(cnt, Cown + 64u * (unsigned int)t);
                __syncthreads();
            }

            const unsigned int* A1p = g_h1 + (long long)t * (64 * 512) + arow * 512;
            gemm_h<1>(ntile, lane, lcol, kch, A1p, sBhi, sBlo, acc_zr, acc_hh);

            const float hn = epilogue_hn(tid, mtile, ntile, lane, lcol,
                                         acc_zr, acc_xh, acc_hh,
                                         sAcc, sBias, hprev, false, 0.f, 0.f, 0.f);
            hprev = hn;
            {
                unsigned short hi_, lo_;
                f2hilo(hn, hi_, lo_);
                const unsigned int pk = ((unsigned int)hi_ << 16) | (unsigned int)lo_;
                unsigned int* dst = g_h1 + (long long)(t + 1) * (64 * 512)
                                  + (long long)(g * 32 + ml) * 512 + (c0 + colw);
                __hip_atomic_store(dst, pk, __ATOMIC_RELAXED, __HIP_MEMORY_SCOPE_AGENT);
                if (t == T_STEPS - 1)
                    out[(g * 32 + ml) * 512 + (c0 + colw)] = hn;
            }
            __syncthreads();   // per-wave vmcnt(0) drain before counter add
            if (tid == 0)
                __hip_atomic_fetch_add(cnt, 1u, __ATOMIC_RELAXED, __HIP_MEMORY_SCOPE_AGENT);
        }
    }
}

extern "C" void kernel_launch(void* const* d_in, const int* in_sizes, int n_in,
                              void* d_out, int out_size, void* d_ws, size_t ws_size,
                              hipStream_t stream) {
    (void)in_sizes; (void)n_in; (void)d_ws; (void)ws_size; (void)out_size;
    const float* x  = (const float*)d_in[0];
    const float* W0 = (const float*)d_in[1];
    const float* U0 = (const float*)d_in[2];
    const float* b0 = (const float*)d_in[3];
    const float* W1 = (const float*)d_in[4];
    const float* U1 = (const float*)d_in[5];
    const float* b1 = (const float*)d_in[6];
    float* out = (float*)d_out;

    (void)hipFuncSetAttribute((const void*)gru_persistent,
                              hipFuncAttributeMaxDynamicSharedMemorySize, SMEM_BYTES);
    void* args[] = {&x, &W0, &U0, &b0, &W1, &U1, &b1, &out};
    hipError_t e = hipLaunchCooperativeKernel((const void*)gru_persistent,
                                              dim3(NWG), dim3(NTHR),
                                              args, SMEM_BYTES, stream);
    if (e != hipSuccess) {
        gru_persistent<<<dim3(NWG), dim3(NTHR), SMEM_BYTES, stream>>>(
            x, W0, U0, b0, W1, U1, b1, out);
    }
}

// Round 9
// 11020.653 us; speedup vs baseline: 1.4392x; 1.1907x over previous
//
#include <hip/hip_runtime.h>

// ---------------------------------------------------------------------------
// 2-layer GRU (Keras reset_after=true), B=64, T=1024, D=U=512.
// Round-9b = round-9 (two-level sync tree + round-0 dataflow) with the
// FINAL-PUBLISH DEADLOCK FIX:
//  Round-9's cell0 root was only stored at step starts k=1..1023 (max
//  R0+1023), but cell1's t=1023 waits for R0+1024 -> guaranteed hang.
//  Fix: after cell0's loop, slice-0 aggregates leaves to 8*1024 and
//  publishes root = R0+1024.
//  Recap of the structure:
//  - Diagnosis: period ~10us/step across rounds 0/2/5 regardless of GEMM
//    count; 64 same-word fetch_adds serialize (~150ns each ~ 9.6us) = period.
//  - Sync: per-clique two-level tree. Producers fetch_add 1-of-8 leaf lines
//    (8 parallel chains of 8); slice-0 polls the 8 leaves with 8 lanes and
//    stores a single root; 63 WGs poll the quiet root line.
//  - No phase-1: cell0 issues x register-loads BEFORE its own-wait (HBM
//    latency hides under detect). cell1 issues h0[t] loads before own-wait.
//  - Dataflow/epilogue = round-0/5 verified; split-bf16 hi/lo MFMA.
// ---------------------------------------------------------------------------

typedef __bf16 bf16x8 __attribute__((ext_vector_type(8)));
typedef float  f32x4  __attribute__((ext_vector_type(4)));
typedef unsigned int uint4v __attribute__((ext_vector_type(4)));

#define T_STEPS 1024
#define NWG 256
#define NTHR 256
#define LEAD 8
#define SMEM_BYTES (98304 + 4096 + 128 + 64)

// h0[k] at slot k+1 (slot 0 = zeros); h1[t] at slot t+1. 134 MB each.
__device__ __align__(16) unsigned int g_h0[1025LL * 64 * 512];
__device__ __align__(16) unsigned int g_h1[1025LL * 64 * 512];
// one-time init barrier state (BSS zero; monotone across launches)
__device__ unsigned int g_leaf[8 * 64];
__device__ unsigned int g_root[64];
__device__ unsigned int g_epoch[64];
// per-step two-level counters; every counter on its own 256B line; monotone
__device__ __align__(256) unsigned int g_lf[2][2][8][64];  // [cell][g][leaf]
__device__ __align__(256) unsigned int g_rt[2][2][64];     // [cell][g] root

__device__ __forceinline__ void f2hilo(float f, unsigned short& hi, unsigned short& lo) {
    __bf16 h = (__bf16)f;
    float  fh = (float)h;
    __bf16 l = (__bf16)(f - fh);
    hi = __builtin_bit_cast(unsigned short, h);
    lo = __builtin_bit_cast(unsigned short, l);
}

__device__ __forceinline__ f32x4 mfma16(bf16x8 a, bf16x8 b, f32x4 c) {
    return __builtin_amdgcn_mfma_f32_16x16x32_bf16(a, b, c, 0, 0, 0);
}

__device__ __forceinline__ void unpack2(uint4v v0, uint4v v1, bf16x8& ah, bf16x8& al) {
    uint4v h, l;
    h.x = __builtin_amdgcn_perm(v0.y, v0.x, 0x07060302u);
    h.y = __builtin_amdgcn_perm(v0.w, v0.z, 0x07060302u);
    h.z = __builtin_amdgcn_perm(v1.y, v1.x, 0x07060302u);
    h.w = __builtin_amdgcn_perm(v1.w, v1.z, 0x07060302u);
    l.x = __builtin_amdgcn_perm(v0.y, v0.x, 0x05040100u);
    l.y = __builtin_amdgcn_perm(v0.w, v0.z, 0x05040100u);
    l.z = __builtin_amdgcn_perm(v1.y, v1.x, 0x05040100u);
    l.w = __builtin_amdgcn_perm(v1.w, v1.z, 0x05040100u);
    ah = __builtin_bit_cast(bf16x8, h);
    al = __builtin_bit_cast(bf16x8, l);
}

// ---- split load/compute GEMM pieces (verified round-5 math) ----
__device__ __forceinline__ void load_Ah(const unsigned int* Ap, int kch,
                                        uint4v A0[16], uint4v A1[16]) {
    #pragma unroll
    for (int ks = 0; ks < 16; ++ks) {
        const uint4v* p = (const uint4v*)(Ap + ks * 32 + kch * 8);
        A0[ks] = p[0];
        A1[ks] = p[1];
    }
}

template<int PASS>
__device__ __forceinline__ void compute_h(
    int ntile, int lane, int lcol, int kch,
    const uint4v A0[16], const uint4v A1[16],
    const unsigned short* sBhi, const unsigned short* sBlo,
    f32x4& acc_zr, f32x4& acc_o)
{
    const bf16x8 bzero = {};
    #pragma unroll
    for (int ks = 0; ks < 16; ++ks) {
        bf16x8 ah, al;
        unpack2(A0[ks], A1[ks], ah, al);
        if (ntile == 0) {
            const int o = PASS * 12288 + ks * 512 + lane * 8;
            bf16x8 bh = *(const bf16x8*)(sBhi + o);
            bf16x8 bl = *(const bf16x8*)(sBlo + o);
            acc_zr = mfma16(ah, bh, acc_zr);
            acc_zr = mfma16(ah, bl, acc_zr);
            acc_zr = mfma16(al, bh, acc_zr);
        } else {
            bf16x8 bh = bzero, bl = bzero;
            if (lcol < 8) {
                const int o = PASS * 12288 + 8192 + ks * 256 + (kch * 8 + lcol) * 8;
                bh = *(const bf16x8*)(sBhi + o);
                bl = *(const bf16x8*)(sBlo + o);
            }
            acc_o = mfma16(ah, bh, acc_o);
            acc_o = mfma16(ah, bl, acc_o);
            acc_o = mfma16(al, bh, acc_o);
        }
    }
}

__device__ __forceinline__ void load_Ax(const float* A, int kch,
                                        float4 F0[16], float4 F1[16]) {
    #pragma unroll
    for (int ks = 0; ks < 16; ++ks) {
        const float4* p = (const float4*)(A + ks * 32 + kch * 8);
        F0[ks] = p[0];
        F1[ks] = p[1];
    }
}

// x @ W0 (PASS=0 region), verified round-2/5 phase-1 math
__device__ __forceinline__ void compute_x(
    int ntile, int lane, int lcol, int kch,
    const float4 F0[16], const float4 F1[16],
    const unsigned short* sBhi, const unsigned short* sBlo,
    f32x4& acc_zr, f32x4& acc_xh)
{
    const bf16x8 bzero = {};
    #pragma unroll
    for (int ks = 0; ks < 16; ++ks) {
        float f[8] = {F0[ks].x, F0[ks].y, F0[ks].z, F0[ks].w,
                      F1[ks].x, F1[ks].y, F1[ks].z, F1[ks].w};
        bf16x8 ah, al;
        #pragma unroll
        for (int i = 0; i < 8; ++i) {
            __bf16 hv = (__bf16)f[i];
            ah[i] = hv;
            al[i] = (__bf16)(f[i] - (float)hv);
        }
        if (ntile == 0) {
            const int o = ks * 512 + lane * 8;
            bf16x8 bh = *(const bf16x8*)(sBhi + o);
            bf16x8 bl = *(const bf16x8*)(sBlo + o);
            acc_zr = mfma16(ah, bh, acc_zr);
            acc_zr = mfma16(ah, bl, acc_zr);
            acc_zr = mfma16(al, bh, acc_zr);
        } else {
            bf16x8 bh = bzero, bl = bzero;
            if (lcol < 8) {
                const int o = 8192 + ks * 256 + (kch * 8 + lcol) * 8;
                bh = *(const bf16x8*)(sBhi + o);
                bl = *(const bf16x8*)(sBlo + o);
            }
            acc_xh = mfma16(ah, bh, acc_xh);
            acc_xh = mfma16(ah, bl, acc_xh);
            acc_xh = mfma16(al, bh, acc_xh);
        }
    }
}

// pack a weight slice into LDS (B-frag layout), bf16 hi/lo (verified)
__device__ __forceinline__ void pack_weights(
    const float* Wm, const float* Um, int c0, int tid,
    unsigned short* sBhi, unsigned short* sBlo)
{
    for (int e = tid; e < 24576; e += NTHR) {
        const int pass = e / 12288;
        const int rem  = e % 12288;
        int j, gcol;
        if (rem < 8192) {
            const int ks = rem >> 9, r2 = rem & 511;
            const int entry = r2 >> 3, i = r2 & 7;
            const int col = entry & 15, kch = entry >> 4;
            j = ks * 32 + kch * 8 + i;
            gcol = (col < 8) ? (c0 + col) : (512 + c0 + col - 8);
        } else {
            const int r2 = rem - 8192;
            const int ks = r2 >> 8, r3 = r2 & 255;
            const int entry = r3 >> 3, i = r3 & 7;
            const int col = entry & 7, kch = entry >> 3;
            j = ks * 32 + kch * 8 + i;
            gcol = 1024 + c0 + col;
        }
        const float v = (pass ? Um : Wm)[j * 1536 + gcol];
        f2hilo(v, sBhi[e], sBlo[e]);
    }
}

// scalar poll with backoff; returns last value seen
__device__ __forceinline__ unsigned int spin_until(unsigned int* C, unsigned int target) {
    int spins = 0;
    for (;;) {
        unsigned int v = __hip_atomic_load(C, __ATOMIC_RELAXED, __HIP_MEMORY_SCOPE_AGENT);
        if ((int)(v - target) >= 0) return v;
        if (spins < 6) __builtin_amdgcn_s_sleep(1);
        else           __builtin_amdgcn_s_sleep(4);
        ++spins;
    }
}

// epilogue (verified round-0 math): accs -> gates -> hn (per thread ml,col)
__device__ __forceinline__ float epilogue_hn(
    int tid, int mtile, int ntile, int lane, int lcol,
    const f32x4& acc_zr, const f32x4& acc_xh, const f32x4& acc_hh,
    float* sAcc, const float* sBias, float hp)
{
    const int drow = mtile * 16 + (lane >> 4) * 4;
    if (ntile == 0) {
        #pragma unroll
        for (int r2 = 0; r2 < 4; ++r2) sAcc[(drow + r2) * 16 + lcol] = acc_zr[r2];
    } else if (lcol < 8) {
        #pragma unroll
        for (int r2 = 0; r2 < 4; ++r2) {
            sAcc[512 + (drow + r2) * 8 + lcol] = acc_xh[r2];
            sAcc[768 + (drow + r2) * 8 + lcol] = acc_hh[r2];
        }
    }
    __syncthreads();
    const int ml  = tid >> 3;
    const int col = tid & 7;
    const float zp = sAcc[ml * 16 + col]     + sBias[col];
    const float rp = sAcc[ml * 16 + 8 + col] + sBias[8 + col];
    const float z = 1.f / (1.f + __expf(-zp));
    const float r = 1.f / (1.f + __expf(-rp));
    const float xh = sAcc[512 + ml * 8 + col] + sBias[16 + col];
    const float hh = sAcc[768 + ml * 8 + col] + sBias[24 + col];
    const float ct = tanhf(xh + r * hh);
    return z * hp + (1.f - z) * ct;
}

__global__ void __launch_bounds__(NTHR, 1) gru_persistent(
    const float* __restrict__ x,  const float* __restrict__ W0,
    const float* __restrict__ U0, const float* __restrict__ b0,
    const float* __restrict__ W1, const float* __restrict__ U1,
    const float* __restrict__ b1, float* __restrict__ out)
{
    extern __shared__ char smem[];
    unsigned short* sBhi = (unsigned short*)smem;
    unsigned short* sBlo = sBhi + 24576;
    float* sAcc   = (float*)(smem + 98304);    // 1024 floats
    float* sBias  = sAcc + 1024;               // 32 floats
    unsigned int* sE0 = (unsigned int*)(sBias + 32);   // 8 u32
    unsigned int* sLB = sE0 + 8;                       // 8 u32 leaf bases

    const int wg    = blockIdx.x;
    const int g     = wg >> 7;
    const int cell  = (wg >> 6) & 1;
    const int slice = wg & 63;
    const int c0    = slice * 8;
    const int tid   = threadIdx.x;

    // kill stale L1/L2 lines from a previous launch
    __builtin_amdgcn_fence(__ATOMIC_ACQUIRE, "agent");

    // counter bases: read before the init grid-barrier (no adds until after it)
    if (tid == 0) {
        sE0[0] = __hip_atomic_load(&g_epoch[0], __ATOMIC_RELAXED, __HIP_MEMORY_SCOPE_AGENT);
        sE0[1] = __hip_atomic_load(&g_rt[cell][g][0], __ATOMIC_RELAXED, __HIP_MEMORY_SCOPE_AGENT);
        sE0[2] = __hip_atomic_load(&g_rt[0][g][0], __ATOMIC_RELAXED, __HIP_MEMORY_SCOPE_AGENT);
        sE0[3] = __hip_atomic_load(&g_rt[1][g][0], __ATOMIC_RELAXED, __HIP_MEMORY_SCOPE_AGENT);
    }
    if (tid < 8)
        sLB[tid] = __hip_atomic_load(&g_lf[cell][g][tid][0], __ATOMIC_RELAXED,
                                     __HIP_MEMORY_SCOPE_AGENT);

    // zero own region of slot 0 (h[-1] = 0)
    {
        const int mlz = tid >> 3, colz = tid & 7;
        unsigned int* dst = (cell ? g_h1 : g_h0)
                          + (long long)(g * 32 + mlz) * 512 + (c0 + colz);
        __hip_atomic_store(dst, 0u, __ATOMIC_RELAXED, __HIP_MEMORY_SCOPE_AGENT);
    }

    // weights: pass0 <- W(own cell), pass1 <- U(own cell). Packed ONCE.
    pack_weights(cell ? W1 : W0, cell ? U1 : U0, c0, tid, sBhi, sBlo);

    // biases
    {
        const float* b = cell ? b1 : b0;
        if (tid < 32) {
            const int col = tid & 7, sec = tid >> 3;
            float v;
            if (sec == 0)      v = b[c0 + col] + b[1536 + c0 + col];
            else if (sec == 1) v = b[512 + c0 + col] + b[1536 + 512 + c0 + col];
            else if (sec == 2) v = b[1024 + c0 + col];
            else               v = b[1536 + 1024 + c0 + col];
            sBias[tid] = v;
        }
    }
    __syncthreads();
    const unsigned int E0   = sE0[0];
    const unsigned int Rown = sE0[1];
    const unsigned int R0   = sE0[2];
    const unsigned int R1   = sE0[3];

    // ---- one-time grid barrier (slot0 zeros + counter bases safe) ----
    {
        const unsigned int target = E0 + 1u;
        if (tid == 0) {
            asm volatile("s_waitcnt vmcnt(0)" ::: "memory");
            unsigned int o = __hip_atomic_fetch_add(&g_leaf[(wg & 7) * 64], 1u,
                                __ATOMIC_RELAXED, __HIP_MEMORY_SCOPE_AGENT);
            if (o == 32u * target - 1u) {
                unsigned int r = __hip_atomic_fetch_add(&g_root[0], 1u,
                                    __ATOMIC_RELAXED, __HIP_MEMORY_SCOPE_AGENT);
                if (r == 8u * target - 1u)
                    __hip_atomic_store(&g_epoch[0], target,
                                       __ATOMIC_RELAXED, __HIP_MEMORY_SCOPE_AGENT);
            }
        }
        while ((int)(__hip_atomic_load(&g_epoch[0], __ATOMIC_RELAXED,
                                       __HIP_MEMORY_SCOPE_AGENT) - target) < 0)
            __builtin_amdgcn_s_sleep(1);
        asm volatile("" ::: "memory");
        __syncthreads();
    }

    const int lane  = tid & 63;
    const int mtile = (tid >> 6) & 1;
    const int ntile = tid >> 7;
    const int lcol  = lane & 15;
    const int kch   = lane >> 4;
    const int arow  = g * 32 + mtile * 16 + lcol;
    const int ml    = tid >> 3;
    const int colw  = tid & 7;

    float hprev = 0.f;

    if (cell == 0) {
        unsigned int* const myleaf = &g_lf[0][g][slice >> 3][0];
        unsigned int* const myroot = &g_rt[0][g][0];
        unsigned int* const bproot = &g_rt[1][g][0];
        unsigned int c1seen = R1;   // meaningful on tid0 only
        for (int k = 0; k < T_STEPS; ++k) {
            // issue x A-loads BEFORE the wait (HBM latency hides under detect)
            float4 F0[16], F1[16];
            load_Ax(x + ((long long)arow * 1024 + k) * 512, kch, F0, F1);

            if (k > 0) {
                if (slice == 0) {
                    // aggregator: 8 lanes poll the 8 leaves, then store root
                    if (tid < 8)
                        spin_until(&g_lf[0][g][tid][0], sLB[tid] + 8u * (unsigned int)k);
                    if (tid == 0)
                        __hip_atomic_store(myroot, Rown + (unsigned int)k,
                                           __ATOMIC_RELAXED, __HIP_MEMORY_SCOPE_AGENT);
                } else if (tid == 0) {
                    spin_until(myroot, Rown + (unsigned int)k);
                }
                // backpressure: cell1 within LEAD steps (cached skip)
                if (tid == 0 && k > LEAD) {
                    const unsigned int bt = R1 + (unsigned int)(k - LEAD);
                    if ((int)(c1seen - bt) < 0)
                        c1seen = spin_until(bproot, bt);
                }
                __syncthreads();   // release WG; x-loads drain here too
            }

            // issue h0[k-1] A-loads (ready after wait); overlap with compute_x
            uint4v A0[16], A1[16];
            load_Ah(g_h0 + (long long)k * (64 * 512) + arow * 512, kch, A0, A1);

            f32x4 acc_zr = {0.f, 0.f, 0.f, 0.f};
            f32x4 acc_xh = {0.f, 0.f, 0.f, 0.f};
            f32x4 acc_hh = {0.f, 0.f, 0.f, 0.f};
            compute_x(ntile, lane, lcol, kch, F0, F1, sBhi, sBlo, acc_zr, acc_xh);
            compute_h<1>(ntile, lane, lcol, kch, A0, A1, sBhi, sBlo, acc_zr, acc_hh);

            const float hn = epilogue_hn(tid, mtile, ntile, lane, lcol,
                                         acc_zr, acc_xh, acc_hh, sAcc, sBias, hprev);
            hprev = hn;
            {
                unsigned short hi_, lo_;
                f2hilo(hn, hi_, lo_);
                const unsigned int pk = ((unsigned int)hi_ << 16) | (unsigned int)lo_;
                unsigned int* dst = g_h0 + (long long)(k + 1) * (64 * 512)
                                  + (long long)(g * 32 + ml) * 512 + (c0 + colw);
                __hip_atomic_store(dst, pk, __ATOMIC_RELAXED, __HIP_MEMORY_SCOPE_AGENT);
            }
            __syncthreads();   // per-wave vmcnt(0) drain before leaf add
            if (tid == 0)
                __hip_atomic_fetch_add(myleaf, 1u, __ATOMIC_RELAXED, __HIP_MEMORY_SCOPE_AGENT);
        }
        // FINAL PUBLISH (deadlock fix): root = R0 + T_STEPS releases cell1's
        // last step (t=1023 waits for R0+1024, never stored by the loop).
        if (slice == 0) {
            if (tid < 8)
                spin_until(&g_lf[0][g][tid][0], sLB[tid] + 8u * (unsigned int)T_STEPS);
            if (tid == 0)
                __hip_atomic_store(myroot, Rown + (unsigned int)T_STEPS,
                                   __ATOMIC_RELAXED, __HIP_MEMORY_SCOPE_AGENT);
        }
    } else {
        unsigned int* const myleaf = &g_lf[1][g][slice >> 3][0];
        unsigned int* const myroot = &g_rt[1][g][0];
        unsigned int* const uproot = &g_rt[0][g][0];
        unsigned int upseen = R0;   // meaningful on tid0 only
        for (int t = 0; t < T_STEPS; ++t) {
            // upstream: h0[t] published when cell0 root >= R0 + t+1 (cached skip)
            if (tid == 0) {
                const unsigned int ut = R0 + (unsigned int)(t + 1);
                if ((int)(upseen - ut) < 0)
                    upseen = spin_until(uproot, ut);
            }
            __syncthreads();

            // issue h0[t] A-loads BEFORE own-wait (latency hides under detect)
            uint4v A0a[16], A0b[16];
            load_Ah(g_h0 + (long long)(t + 1) * (64 * 512) + arow * 512, kch, A0a, A0b);

            if (t > 0) {
                if (slice == 0) {
                    if (tid < 8)
                        spin_until(&g_lf[1][g][tid][0], sLB[tid] + 8u * (unsigned int)t);
                    if (tid == 0)
                        __hip_atomic_store(myroot, Rown + (unsigned int)t,
                                           __ATOMIC_RELAXED, __HIP_MEMORY_SCOPE_AGENT);
                } else if (tid == 0) {
                    spin_until(myroot, Rown + (unsigned int)t);
                }
                __syncthreads();   // release; A0 loads drain here
            }

            // issue h1[t-1] A-loads; overlap with gemm0 compute
            uint4v A1a[16], A1b[16];
            load_Ah(g_h1 + (long long)t * (64 * 512) + arow * 512, kch, A1a, A1b);

            f32x4 acc_zr = {0.f, 0.f, 0.f, 0.f};
            f32x4 acc_xh = {0.f, 0.f, 0.f, 0.f};
            f32x4 acc_hh = {0.f, 0.f, 0.f, 0.f};
            compute_h<0>(ntile, lane, lcol, kch, A0a, A0b, sBhi, sBlo, acc_zr, acc_xh);
            compute_h<1>(ntile, lane, lcol, kch, A1a, A1b, sBhi, sBlo, acc_zr, acc_hh);

            const float hn = epilogue_hn(tid, mtile, ntile, lane, lcol,
                                         acc_zr, acc_xh, acc_hh, sAcc, sBias, hprev);
            hprev = hn;
            {
                unsigned short hi_, lo_;
                f2hilo(hn, hi_, lo_);
                const unsigned int pk = ((unsigned int)hi_ << 16) | (unsigned int)lo_;
                unsigned int* dst = g_h1 + (long long)(t + 1) * (64 * 512)
                                  + (long long)(g * 32 + ml) * 512 + (c0 + colw);
                __hip_atomic_store(dst, pk, __ATOMIC_RELAXED, __HIP_MEMORY_SCOPE_AGENT);
                if (t == T_STEPS - 1)
                    out[(g * 32 + ml) * 512 + (c0 + colw)] = hn;
            }
            __syncthreads();   // per-wave vmcnt(0) drain before leaf add
            if (tid == 0)
                __hip_atomic_fetch_add(myleaf, 1u, __ATOMIC_RELAXED, __HIP_MEMORY_SCOPE_AGENT);
        }
    }
}

extern "C" void kernel_launch(void* const* d_in, const int* in_sizes, int n_in,
                              void* d_out, int out_size, void* d_ws, size_t ws_size,
                              hipStream_t stream) {
    (void)in_sizes; (void)n_in; (void)d_ws; (void)ws_size; (void)out_size;
    const float* x  = (const float*)d_in[0];
    const float* W0 = (const float*)d_in[1];
    const float* U0 = (const float*)d_in[2];
    const float* b0 = (const float*)d_in[3];
    const float* W1 = (const float*)d_in[4];
    const float* U1 = (const float*)d_in[5];
    const float* b1 = (const float*)d_in[6];
    float* out = (float*)d_out;

    (void)hipFuncSetAttribute((const void*)gru_persistent,
                              hipFuncAttributeMaxDynamicSharedMemorySize, SMEM_BYTES);
    void* args[] = {&x, &W0, &U0, &b0, &W1, &U1, &b1, &out};
    hipError_t e = hipLaunchCooperativeKernel((const void*)gru_persistent,
                                              dim3(NWG), dim3(NTHR),
                                              args, SMEM_BYTES, stream);
    if (e != hipSuccess) {
        gru_persistent<<<dim3(NWG), dim3(NTHR), SMEM_BYTES, stream>>>(
            x, W0, U0, b0, W1, U1, b1, out);
    }
}